// Round 1
// baseline (388.257 us; speedup 1.0000x reference)
//
#include <hip/hip_runtime.h>
#include <math.h>

#define H 512
#define W 512
#define NB 8
#define PLANE (H*W)       // 262144
#define PLANE4 (PLANE/4)  // 65536

// ---------------- v = (r+g+b)/3 ----------------
__launch_bounds__(256)
__global__ void k_gray(const float* __restrict__ x, float* __restrict__ v){
  int id = blockIdx.x*256 + threadIdx.x;   // NB*PLANE4 = 524288
  int b = id >> 16, p = id & 65535;
  const float4* xr = (const float4*)(x + (size_t)(b*3+0)*PLANE);
  const float4* xg = (const float4*)(x + (size_t)(b*3+1)*PLANE);
  const float4* xb = (const float4*)(x + (size_t)(b*3+2)*PLANE);
  float4 R = xr[p], G = xg[p], Bl = xb[p], o;
  o.x = (R.x+G.x+Bl.x)/3.f; o.y = (R.y+G.y+Bl.y)/3.f;
  o.z = (R.z+G.z+Bl.z)/3.f; o.w = (R.w+G.w+Bl.w)/3.f;
  ((float4*)(v + (size_t)b*PLANE))[p] = o;
}

// ---------------- generic 3x3 conv, pad=1, stride=1 ----------------
// input = concat(in1[INC1 ch], in2[INC2 ch]); ACT: 0=relu, 1=sigmoid
template<int INC1, int INC2, int OUTC, int ACT>
__launch_bounds__(256)
__global__ void k_conv3(const float* __restrict__ in1, const float* __restrict__ in2,
                        const float* __restrict__ wgt, const float* __restrict__ bias,
                        float* __restrict__ out){
  constexpr int INC = INC1 + INC2;
  __shared__ float wl[OUTC*INC*9];
  for (int i = threadIdx.x; i < OUTC*INC*9; i += 256) wl[i] = wgt[i];
  __syncthreads();
  int id  = blockIdx.x*256 + threadIdx.x;  // NB*H*(W/4) = 524288
  int b   = id >> 16;
  int rem = id & 65535;
  int y   = rem >> 7;
  int x0  = (rem & 127) << 2;
  float acc[OUTC][4];
  #pragma unroll
  for (int co=0; co<OUTC; ++co){
    float bv = bias[co];
    #pragma unroll
    for (int k=0;k<4;++k) acc[co][k] = bv;
  }
  #pragma unroll
  for (int ci=0; ci<INC; ++ci){
    const float* sp = (ci < INC1)
        ? (in1 + (size_t)(b*INC1 + ci)*PLANE)
        : (in2 + (size_t)(b*INC2 + (ci-INC1))*PLANE);
    float r[3][6];
    #pragma unroll
    for (int dy=0; dy<3; ++dy){
      int yy = y + dy - 1;
      bool yok = (unsigned)yy < (unsigned)H;
      const float* row = sp + yy*W;
      #pragma unroll
      for (int dx=0; dx<6; ++dx){
        int xx = x0 + dx - 1;
        r[dy][dx] = (yok && ((unsigned)xx < (unsigned)W)) ? row[xx] : 0.f;
      }
    }
    #pragma unroll
    for (int co=0; co<OUTC; ++co){
      #pragma unroll
      for (int dy=0; dy<3; ++dy){
        #pragma unroll
        for (int dx=0; dx<3; ++dx){
          float wv = wl[(co*INC+ci)*9 + dy*3 + dx];
          #pragma unroll
          for (int k=0;k<4;++k) acc[co][k] += r[dy][dx+k]*wv;
        }
      }
    }
  }
  #pragma unroll
  for (int co=0; co<OUTC; ++co){
    float4 o;
    if (ACT == 0){
      o.x = fmaxf(acc[co][0],0.f); o.y = fmaxf(acc[co][1],0.f);
      o.z = fmaxf(acc[co][2],0.f); o.w = fmaxf(acc[co][3],0.f);
    } else {
      o.x = 1.f/(1.f+expf(-acc[co][0])); o.y = 1.f/(1.f+expf(-acc[co][1]));
      o.z = 1.f/(1.f+expf(-acc[co][2])); o.w = 1.f/(1.f+expf(-acc[co][3]));
    }
    *(float4*)(out + (size_t)(b*OUTC+co)*PLANE + y*W + x0) = o;
  }
}

// ---------------- subsample + m-conv(stride2) + leaky + instance norm -> src(S,B,E) ----------------
__launch_bounds__(256)
__global__ void k_mnorm(const float* __restrict__ v, const float* __restrict__ mw,
                        const float* __restrict__ mb, const float* __restrict__ ing,
                        const float* __restrict__ inb, float* __restrict__ src){
  int bc = blockIdx.x;           // 128 = b*16+c
  int b = bc >> 4, c = bc & 15;
  int tid = threadIdx.x;         // 256 = out pixel (i*16+j)
  int i = tid >> 4, j = tid & 15;
  float s = mb[c];
  #pragma unroll
  for (int dy=0; dy<3; ++dy){
    int ii = 2*i - 1 + dy;
    if ((unsigned)ii >= 32u) continue;
    #pragma unroll
    for (int dx=0; dx<3; ++dx){
      int jj = 2*j - 1 + dx;
      if ((unsigned)jj >= 32u) continue;
      // v32[ii][jj] = v[b][16*ii][16*jj]
      s += v[(size_t)b*PLANE + (ii*16)*W + jj*16] * mw[c*9 + dy*3 + dx];
    }
  }
  float h = (s >= 0.f) ? s : 0.2f*s;
  __shared__ float red[256];
  red[tid] = h; __syncthreads();
  for (int off=128; off; off>>=1){ if (tid<off) red[tid]+=red[tid+off]; __syncthreads(); }
  float mu = red[0] * (1.f/256.f);
  __syncthreads();
  float d = h - mu;
  red[tid] = d*d; __syncthreads();
  for (int off=128; off; off>>=1){ if (tid<off) red[tid]+=red[tid+off]; __syncthreads(); }
  float var = red[0] * (1.f/256.f);
  float yv = d * rsqrtf(var + 1e-5f) * ing[c] + inb[c];
  src[(size_t)tid*128 + b*16 + c] = yv;   // src[s][b][e], s=tid
}

// ---------------- qkv projection ----------------
__launch_bounds__(256)
__global__ void k_qkv(const float* __restrict__ src, const float* __restrict__ aw,
                      const float* __restrict__ ab, float* __restrict__ qkv){
  int id = blockIdx.x*256 + threadIdx.x;  // 2048*48 = 98304
  int tok = id / 48, o = id % 48;
  const float* sr = src + tok*16;
  float s = ab[o];
  #pragma unroll
  for (int e=0; e<16; ++e) s += sr[e]*aw[o*16+e];
  qkv[tok*48+o] = s;
}

// ---------------- attention (per b,h block; head dim = 2) ----------------
__launch_bounds__(256)
__global__ void k_attn(const float* __restrict__ qkv, float* __restrict__ obuf){
  int b = blockIdx.x >> 3, hh = blockIdx.x & 7;  // 64 blocks
  int t = threadIdx.x;                           // s index
  __shared__ float kk0[256], kk1[256], vv0[256], vv1[256];
  int tok = t*8 + b;
  const float* qr = qkv + tok*48;
  kk0[t] = qr[16 + hh*2]; kk1[t] = qr[16 + hh*2 + 1];
  vv0[t] = qr[32 + hh*2]; vv1[t] = qr[32 + hh*2 + 1];
  float q0 = qr[hh*2], q1 = qr[hh*2 + 1];
  __syncthreads();
  const float sc = 0.70710678118654752f;  // 1/sqrt(2)
  float m = -1e30f;
  for (int u=0; u<256; ++u){
    float s = (q0*kk0[u] + q1*kk1[u]) * sc;
    m = fmaxf(m, s);
  }
  float l = 0.f, a0 = 0.f, a1 = 0.f;
  for (int u=0; u<256; ++u){
    float s = (q0*kk0[u] + q1*kk1[u]) * sc;
    float p = expf(s - m);
    l += p; a0 += p*vv0[u]; a1 += p*vv1[u];
  }
  float inv = 1.f/l;
  obuf[tok*16 + hh*2]     = a0*inv;
  obuf[tok*16 + hh*2 + 1] = a1*inv;
}

// ---------------- out-proj + residual + layernorm1 (in-place on src) ----------------
__launch_bounds__(256)
__global__ void k_oproj_ln(const float* __restrict__ obuf, const float* __restrict__ ow,
                           const float* __restrict__ obias, const float* __restrict__ g,
                           const float* __restrict__ bb, float* __restrict__ src){
  int tok = blockIdx.x*256 + threadIdx.x;  // 2048
  const float* orow = obuf + tok*16;
  float xv[16];
  #pragma unroll
  for (int e=0; e<16; ++e){
    float s = obias[e];
    #pragma unroll
    for (int f=0; f<16; ++f) s += orow[f]*ow[e*16+f];
    xv[e] = src[tok*16+e] + s;
  }
  float mu = 0.f;
  #pragma unroll
  for (int e=0; e<16; ++e) mu += xv[e];
  mu *= (1.f/16.f);
  float var = 0.f;
  #pragma unroll
  for (int e=0; e<16; ++e){ float d = xv[e]-mu; var += d*d; }
  var *= (1.f/16.f);
  float rs = rsqrtf(var + 1e-5f);
  #pragma unroll
  for (int e=0; e<16; ++e) src[tok*16+e] = (xv[e]-mu)*rs*g[e] + bb[e];
}

// ---------------- FFN + residual + layernorm2 (in-place on src) ----------------
__launch_bounds__(64)
__global__ void k_ffn_ln(float* __restrict__ src, const float* __restrict__ w1,
                         const float* __restrict__ b1, const float* __restrict__ w2,
                         const float* __restrict__ b2, const float* __restrict__ g,
                         const float* __restrict__ bb){
  int tok = blockIdx.x;     // 2048
  int tid = threadIdx.x;    // 64
  __shared__ float srow[16], h1[128], xr[16];
  if (tid < 16) srow[tid] = src[tok*16+tid];
  __syncthreads();
  for (int i = tid; i < 128; i += 64){
    float s = b1[i];
    #pragma unroll
    for (int e=0; e<16; ++e) s += srow[e]*w1[i*16+e];
    h1[i] = fmaxf(s, 0.f);
  }
  __syncthreads();
  if (tid < 16){
    float s = b2[tid];
    for (int j=0; j<128; ++j) s += h1[j]*w2[tid*128+j];
    xr[tid] = srow[tid] + s;
  }
  __syncthreads();
  if (tid < 16){
    float mu = 0.f;
    #pragma unroll
    for (int e=0; e<16; ++e) mu += xr[e];
    mu *= (1.f/16.f);
    float var = 0.f;
    #pragma unroll
    for (int e=0; e<16; ++e){ float d = xr[e]-mu; var += d*d; }
    var *= (1.f/16.f);
    src[tok*16+tid] = (xr[tid]-mu)*rsqrtf(var+1e-5f)*g[tid] + bb[tid];
  }
}

// ---------------- final 16x16 valid conv -> level -> g/bcf scalars ----------------
__launch_bounds__(256)
__global__ void k_level(const float* __restrict__ src, const float* __restrict__ fw,
                        const float* __restrict__ fb, float* __restrict__ gb){
  int b = blockIdx.x >> 1, k = blockIdx.x & 1;  // 16 blocks
  int tid = threadIdx.x;                        // s pixel
  float s = 0.f;
  #pragma unroll
  for (int c=0; c<16; ++c)
    s += src[(size_t)tid*128 + b*16 + c] * fw[(k*16+c)*256 + tid];
  __shared__ float red[256];
  red[tid] = s; __syncthreads();
  for (int off=128; off; off>>=1){ if (tid<off) red[tid]+=red[tid+off]; __syncthreads(); }
  if (tid == 0){
    float lev = 1.f/(1.f + expf(-(red[0] + fb[k])));
    gb[b*2+k] = (k==0) ? (0.1f*lev + 0.2f) : (0.04f*lev + 0.06f);
  }
}

// ---------------- final elementwise: enhance + t ----------------
__launch_bounds__(256)
__global__ void k_final(const float* __restrict__ x, const float* __restrict__ gb,
                        float* __restrict__ out){
  int id = blockIdx.x*256 + threadIdx.x;  // 524288
  int b = id >> 16, p = id & 65535;
  const float4* xr = (const float4*)(x + (size_t)(b*3+0)*PLANE);
  const float4* xg = (const float4*)(x + (size_t)(b*3+1)*PLANE);
  const float4* xb = (const float4*)(x + (size_t)(b*3+2)*PLANE);
  const float4* vrp = (const float4*)(out + 6291456 + (size_t)b*PLANE);
  float4 R = xr[p], G = xg[p], Bl = xb[p], VR = vrp[p];
  float gg = gb[b*2+0], bc = gb[b*2+1];
  float lg = log2f(gg);
  float4 er, eg, eb, tr, tg, tb;
#define COMP(SUF, RF, GF, BF, VRF) {            \
    float vv = (RF + GF + BF)/3.f;              \
    float v0 = fminf(fmaxf(vv, 1e-6f), 0.999999f); \
    float r0 = exp2f(VRF * lg);                 \
    float ev0 = exp2f(r0 * log2f(v0));          \
    float d = bc - vv;                          \
    float L = 400.f*d*d*d;                      \
    L = (L < 1e-5f) ? 1e-6f : L;                \
    float fac = (ev0 - L) / (vv + 1e-6f);       \
    er.SUF = RF*fac; eg.SUF = GF*fac; eb.SUF = BF*fac; \
    bool z = vv > 0.04f;                        \
    tr.SUF = z ? 0.f : er.SUF; tg.SUF = z ? 0.f : eg.SUF; tb.SUF = z ? 0.f : eb.SUF; }
  COMP(x, R.x, G.x, Bl.x, VR.x)
  COMP(y, R.y, G.y, Bl.y, VR.y)
  COMP(z, R.z, G.z, Bl.z, VR.z)
  COMP(w, R.w, G.w, Bl.w, VR.w)
#undef COMP
  float4* oe = (float4*)out;
  float4* ot = (float4*)(out + 8388608);
  oe[(size_t)(b*3+0)*PLANE4 + p] = er;
  oe[(size_t)(b*3+1)*PLANE4 + p] = eg;
  oe[(size_t)(b*3+2)*PLANE4 + p] = eb;
  ot[(size_t)(b*3+0)*PLANE4 + p] = tr;
  ot[(size_t)(b*3+1)*PLANE4 + p] = tg;
  ot[(size_t)(b*3+2)*PLANE4 + p] = tb;
}

extern "C" void kernel_launch(void* const* d_in, const int* in_sizes, int n_in,
                              void* d_out, int out_size, void* d_ws, size_t ws_size,
                              hipStream_t stream) {
  const float* x    = (const float*)d_in[0];
  const float* c1w  = (const float*)d_in[1];  const float* c1b = (const float*)d_in[2];
  const float* c2w  = (const float*)d_in[3];  const float* c2b = (const float*)d_in[4];
  const float* c3w  = (const float*)d_in[5];  const float* c3b = (const float*)d_in[6];
  const float* c4w  = (const float*)d_in[7];  const float* c4b = (const float*)d_in[8];
  const float* c5w  = (const float*)d_in[9];  const float* c5b = (const float*)d_in[10];
  const float* c6w  = (const float*)d_in[11]; const float* c6b = (const float*)d_in[12];
  const float* c7w  = (const float*)d_in[13]; const float* c7b = (const float*)d_in[14];
  const float* mw   = (const float*)d_in[15]; const float* mb  = (const float*)d_in[16];
  const float* ing  = (const float*)d_in[17]; const float* inb = (const float*)d_in[18];
  const float* aw   = (const float*)d_in[19]; const float* ab  = (const float*)d_in[20];
  const float* ow   = (const float*)d_in[21]; const float* ob  = (const float*)d_in[22];
  const float* l1w  = (const float*)d_in[23]; const float* l1b = (const float*)d_in[24];
  const float* l2w  = (const float*)d_in[25]; const float* l2b = (const float*)d_in[26];
  const float* n1g  = (const float*)d_in[27]; const float* n1b = (const float*)d_in[28];
  const float* n2g  = (const float*)d_in[29]; const float* n2b = (const float*)d_in[30];
  const float* fw   = (const float*)d_in[31]; const float* fb  = (const float*)d_in[32];

  float* Wp  = (float*)d_ws;
  float* v    = Wp;                    // 2,097,152
  float* A    = v   + 2097152;         // x1: 8,388,608
  float* Bb   = A   + 8388608;         // x2
  float* C    = Bb  + 8388608;         // x3, later x6
  float* D    = C   + 8388608;         // x4
  float* E    = D   + 8388608;         // x5
  float* src  = E   + 8388608;         // 32,768
  float* qkv  = src + 32768;           // 98,304
  float* obuf = qkv + 98304;           // 32,768
  float* gb   = obuf+ 32768;           // 16
  float* out  = (float*)d_out;
  float* vr   = out + 6291456;         // v_r output region

  k_gray<<<2048,256,0,stream>>>(x, v);
  k_conv3<1,0,4,0><<<2048,256,0,stream>>>(v,  nullptr, c1w, c1b, A);   // x1
  k_conv3<4,0,4,0><<<2048,256,0,stream>>>(A,  nullptr, c2w, c2b, Bb);  // x2
  k_conv3<4,0,4,0><<<2048,256,0,stream>>>(Bb, nullptr, c3w, c3b, C);   // x3
  k_conv3<4,0,4,0><<<2048,256,0,stream>>>(C,  nullptr, c4w, c4b, D);   // x4
  k_conv3<4,4,4,0><<<2048,256,0,stream>>>(C,  D,       c5w, c5b, E);   // x5 = conv([x3,x4])
  k_conv3<4,4,4,0><<<2048,256,0,stream>>>(Bb, E,       c6w, c6b, C);   // x6 = conv([x2,x5])
  k_conv3<4,4,1,1><<<2048,256,0,stream>>>(A,  C,       c7w, c7b, vr);  // v_r = sigmoid(conv([x1,x6]))

  k_mnorm<<<128,256,0,stream>>>(v, mw, mb, ing, inb, src);
  k_qkv<<<384,256,0,stream>>>(src, aw, ab, qkv);
  k_attn<<<64,256,0,stream>>>(qkv, obuf);
  k_oproj_ln<<<8,256,0,stream>>>(obuf, ow, ob, n1g, n1b, src);
  k_ffn_ln<<<2048,64,0,stream>>>(src, l1w, l1b, l2w, l2b, n2g, n2b);
  k_level<<<16,256,0,stream>>>(src, fw, fb, gb);
  k_final<<<2048,256,0,stream>>>(x, gb, out);
}